// Round 6
// baseline (1099.268 us; speedup 1.0000x reference)
//
#include <hip/hip_runtime.h>
#include <math.h>

// TGV-2 PDHG, B=2, H=W=256, T=128.
// R6: persistent cooperative kernel, inline atomic grid barrier (validated in
// R5), but with ZERO register state live across the barrier: each round does
// full reload -> 8 trapezoid iterations -> interior store -> barrier. R4/R5
// showed that holding the 48-float state in registers across the in-kernel
// barrier forces a scratch spill (VGPR=56, FETCH 170MB, 3x slower); the
// non-spilling R3 kernel had exactly this load/iterate/store shape per
// launch. Round 0 derives state from f (u=ub=f, rest 0), so the only init
// is zeroing the barrier counter.
// Geometry (validated): 16x16 tile + halo 8 => 32x32 region, 512 blocks
// (2/CU, co-resident via cooperative launch), 256 threads (4 waves), each
// thread owns a 1x4 strip, LDS only for halo exchange (aligned b128).

namespace {

constexpr int kN = 2 * 256 * 256;
constexpr float kTau = 0.28867513459481287f;  // 1/sqrt(12) (f32)
constexpr float kSigma = kTau;
constexpr float kInv1pTau = 1.0f / (1.0f + kTau);

constexpr int R = 32;           // region side
constexpr int A = R * R;        // 1024 floats per LDS array
constexpr int PAD = 64;         // rim-overread safety pads (front/back)
constexpr int TILE = 16;
constexpr int HALO = 8;         // iterations per round
constexpr int ROUNDS = 128 / HALO;  // 16
constexpr int NTHREADS = R * (R / 4);  // 256 = 4 waves
constexpr unsigned NBLOCKS = 16 * 16 * 2;  // 512

__device__ unsigned g_ctr;  // grid-barrier counter (zeroed by zero_ctr)

__device__ __forceinline__ float4 ld4(const float* p) {
  return *reinterpret_cast<const float4*>(p);
}
__device__ __forceinline__ void st4v(float* p, const float* a) {
  float4 v;
  v.x = a[0]; v.y = a[1]; v.z = a[2]; v.w = a[3];
  *reinterpret_cast<float4*>(p) = v;
}
__device__ __forceinline__ float msel(bool m, float x) { return m ? x : 0.f; }

// Inline grid barrier (validated R5: absmax identical across XCDs).
// target = round * NBLOCKS; counter only grows within one launch.
__device__ __forceinline__ void grid_barrier(unsigned target) {
  __syncthreads();  // drains this block's stores (vmcnt(0) before s_barrier)
  if (threadIdx.x == 0) {
    __threadfence();        // release: block's stores visible device-wide
    atomicAdd(&g_ctr, 1u);  // device-scope by default on gfx950
    while (__hip_atomic_load(&g_ctr, __ATOMIC_RELAXED,
                             __HIP_MEMORY_SCOPE_AGENT) < target) {
      __builtin_amdgcn_s_sleep(2);
    }
    __threadfence();  // acquire: invalidate stale cached lines
  }
  __syncthreads();
}

__global__ void zero_ctr() { g_ctr = 0u; }

// ws layout: 10 arrays of kN floats: ub, v1, v2, vb1, vb2, p1, p2, q11, q22, q12
__global__ __launch_bounds__(NTHREADS, 2) void tgv_persist(
    const float* __restrict__ f, const float* __restrict__ rp,
    float* __restrict__ ug, float* __restrict__ ws) {
  float* ubg = ws + 0 * kN;
  float* v1g = ws + 1 * kN;
  float* v2g = ws + 2 * kN;
  float* vb1g = ws + 3 * kN;
  float* vb2g = ws + 4 * kN;
  float* p1g = ws + 5 * kN;
  float* p2g = ws + 6 * kN;
  float* q11g = ws + 7 * kN;
  float* q22g = ws + 8 * kN;
  float* q12g = ws + 9 * kN;

  __shared__ __align__(16) float smem[PAD + 8 * A + PAD];
  float* ubS = smem + PAD;
  float* vb1S = ubS + A;
  float* vb2S = vb1S + A;
  float* p1S = vb2S + A;
  float* p2S = p1S + A;
  float* q11S = p2S + A;
  float* q22S = q11S + A;
  float* q12S = q22S + A;

  const int tid = threadIdx.x;
  const int r = tid >> 3;       // region row 0..31
  const int c = (tid & 7) * 4;  // region col (float4-aligned)
  const int rc = r * R + c;

  const int gi = blockIdx.y * TILE + r - HALO;  // global row (may be OOB)
  const int gj = blockIdx.x * TILE + c - HALO;  // global col (float4 in/out)
  const bool inImg = ((unsigned)gi < 256u) && ((unsigned)gj < 256u);
  const bool isInterior =
      (r >= HALO && r < HALO + TILE && c >= HALO && c < HALO + TILE);
  const int base = blockIdx.z * 65536 + gi * 256 + gj;

  const float alpha0 = rp[0];
  const float alpha1 = rp[1];

  // image-boundary masks (global coords; garbage positions don't matter)
  const bool hasD = (gi != 255);
  const bool hasU = (gi != 0);

  for (int round = 0; round < ROUNDS; ++round) {
    // ---- (re)load full state; nothing is live across the barrier ----
    float u_[4], ub_[4], v1_[4], v2_[4], vb1_[4], vb2_[4];
    float p1_[4], p2_[4], q11_[4], q22_[4], q12_[4], f_[4];

#define LOADV(dst, src)                                         \
  {                                                             \
    float4 t_ = ld4((src) + base);                              \
    dst[0] = t_.x; dst[1] = t_.y; dst[2] = t_.z; dst[3] = t_.w; \
  }
    if (inImg) {
      LOADV(f_, f)
      if (round == 0) {
        // u = ub = f, all dual/aux state zero
#pragma unroll
        for (int e = 0; e < 4; ++e) {
          u_[e] = f_[e]; ub_[e] = f_[e];
          v1_[e] = 0.f; v2_[e] = 0.f; vb1_[e] = 0.f; vb2_[e] = 0.f;
          p1_[e] = 0.f; p2_[e] = 0.f;
          q11_[e] = 0.f; q22_[e] = 0.f; q12_[e] = 0.f;
        }
      } else {
        LOADV(u_, ug)
        LOADV(ub_, ubg)
        LOADV(v1_, v1g)
        LOADV(v2_, v2g)
        LOADV(vb1_, vb1g)
        LOADV(vb2_, vb2g)
        LOADV(p1_, p1g)
        LOADV(p2_, p2g)
        LOADV(q11_, q11g)
        LOADV(q22_, q22g)
        LOADV(q12_, q12g)
      }
    } else {
#pragma unroll
      for (int e = 0; e < 4; ++e) {
        f_[e] = 0.f; u_[e] = 0.f; ub_[e] = 0.f;
        v1_[e] = 0.f; v2_[e] = 0.f; vb1_[e] = 0.f; vb2_[e] = 0.f;
        p1_[e] = 0.f; p2_[e] = 0.f; q11_[e] = 0.f; q22_[e] = 0.f; q12_[e] = 0.f;
      }
    }
#undef LOADV

    for (int t = 0; t < HALO; ++t) {
      // ---- publish dual halos (ub, vb) ----
      st4v(ubS + rc, ub_);
      st4v(vb1S + rc, vb1_);
      st4v(vb2S + rc, vb2_);
      __syncthreads();

      // ---- dual ascent + projections (updates p,q in registers) ----
      const float ubX = ld4(ubS + rc + 4).x;  // right-edge neighbor, aligned
      const float vb1X = ld4(vb1S + rc + 4).x;
      const float vb2X = ld4(vb2S + rc + 4).x;
      float4 td;
      td = ld4(ubS + rc + R);
      const float ubD[4] = {td.x, td.y, td.z, td.w};
      td = ld4(vb1S + rc + R);
      const float vb1D[4] = {td.x, td.y, td.z, td.w};
      td = ld4(vb2S + rc + R);
      const float vb2D[4] = {td.x, td.y, td.z, td.w};

#pragma unroll
      for (int e = 0; e < 4; ++e) {
        const bool hR = (gj + e != 255);
        const float ubr = (e < 3) ? ub_[e + 1] : ubX;
        const float vb1r = (e < 3) ? vb1_[e + 1] : vb1X;
        const float vb2r = (e < 3) ? vb2_[e + 1] : vb2X;

        const float du1 = msel(hasD, ubD[e] - ub_[e]);  // fwd diff axis1 (H)
        const float du2 = msel(hR, ubr - ub_[e]);       // fwd diff axis2 (W)
        float pn1 = p1_[e] + kSigma * (du1 - vb1_[e]);
        float pn2 = p2_[e] + kSigma * (du2 - vb2_[e]);
        float nrm = sqrtf(pn1 * pn1 + pn2 * pn2);
        float sc = alpha1 * __builtin_amdgcn_rcpf(fmaxf(alpha1, nrm));
        p1_[e] = pn1 * sc;
        p2_[e] = pn2 * sc;

        const float e11 = msel(hasD, vb1D[e] - vb1_[e]);
        const float e22 = msel(hR, vb2r - vb2_[e]);
        const float e12 =
            0.5f * (msel(hR, vb1r - vb1_[e]) + msel(hasD, vb2D[e] - vb2_[e]));
        float qn1 = q11_[e] + kSigma * e11;
        float qn2 = q22_[e] + kSigma * e22;
        float qn3 = q12_[e] + kSigma * e12;
        nrm = sqrtf(qn1 * qn1 + qn2 * qn2 + 2.f * qn3 * qn3);
        sc = alpha0 * __builtin_amdgcn_rcpf(fmaxf(alpha0, nrm));
        q11_[e] = qn1 * sc;
        q22_[e] = qn2 * sc;
        q12_[e] = qn3 * sc;
      }

      // ---- publish primal halos (new p, q) ----
      st4v(p1S + rc, p1_);
      st4v(p2S + rc, p2_);
      st4v(q11S + rc, q11_);
      st4v(q22S + rc, q22_);
      st4v(q12S + rc, q12_);
      __syncthreads();

      // ---- primal descent + over-relaxation ----
      float4 tu;
      tu = ld4(p1S + rc - R);
      const float p1U[4] = {tu.x, tu.y, tu.z, tu.w};
      tu = ld4(q11S + rc - R);
      const float q11U[4] = {tu.x, tu.y, tu.z, tu.w};
      tu = ld4(q12S + rc - R);
      const float q12U[4] = {tu.x, tu.y, tu.z, tu.w};
      const float p2Lx = ld4(p2S + rc - 4).w;  // left-edge neighbor, aligned
      const float q22Lx = ld4(q22S + rc - 4).w;
      const float q12Lx = ld4(q12S + rc - 4).w;

#pragma unroll
      for (int e = 0; e < 4; ++e) {
        const bool hR = (gj + e != 255);
        const bool hL = (e == 0) ? (gj != 0) : true;
        const float p2l = (e == 0) ? p2Lx : p2_[e - 1];
        const float q22l = (e == 0) ? q22Lx : q22_[e - 1];
        const float q12l = (e == 0) ? q12Lx : q12_[e - 1];

        const float divp = msel(hasD, p1_[e]) - msel(hasU, p1U[e]) +
                           msel(hR, p2_[e]) - msel(hL, p2l);
        const float un = (u_[e] + kTau * divp + kTau * f_[e]) * kInv1pTau;
        ub_[e] = 2.f * un - u_[e];
        u_[e] = un;

        const float c1 = msel(hasD, q11_[e]) - msel(hasU, q11U[e]) +
                         msel(hR, q12_[e]) - msel(hL, q12l);
        const float c2 = msel(hasD, q12_[e]) - msel(hasU, q12U[e]) +
                         msel(hR, q22_[e]) - msel(hL, q22l);
        const float v1n = v1_[e] + kTau * (p1_[e] + c1);
        const float v2n = v2_[e] + kTau * (p2_[e] + c2);
        vb1_[e] = 2.f * v1n - v1_[e];
        v1_[e] = v1n;
        vb2_[e] = 2.f * v2n - v2_[e];
        v2_[e] = v2n;
      }
    }

    // ---- store interior 16x16 (exact after 8 iters) ----
    if (isInterior) {
      st4v(ug + base, u_);
      st4v(ubg + base, ub_);
      st4v(v1g + base, v1_);
      st4v(v2g + base, v2_);
      st4v(vb1g + base, vb1_);
      st4v(vb2g + base, vb2_);
      st4v(p1g + base, p1_);
      st4v(p2g + base, p2_);
      st4v(q11g + base, q11_);
      st4v(q22g + base, q22_);
      st4v(q12g + base, q12_);
    }

    if (round + 1 < ROUNDS) {
      grid_barrier((unsigned)(round + 1) * NBLOCKS);
    }
  }
}

}  // namespace

extern "C" void kernel_launch(void* const* d_in, const int* in_sizes, int n_in,
                              void* d_out, int out_size, void* d_ws,
                              size_t ws_size, hipStream_t stream) {
  const float* f = (const float*)d_in[0];
  const float* rp = (const float*)d_in[1];  // [alpha0, alpha1]
  // d_in[2] is T = 128 (fixed; trip count must be static for graph capture).

  float* u = (float*)d_out;
  float* ws = (float*)d_ws;

  hipLaunchKernelGGL(zero_ctr, dim3(1), dim3(1), 0, stream);

  dim3 grid(256 / TILE, 256 / TILE, 2);  // 16 x 16 x 2 = 512 blocks, 2 per CU
  dim3 block(NTHREADS);
  void* args[] = {(void*)&f, (void*)&rp, (void*)&u, (void*)&ws};
  hipLaunchCooperativeKernel((void*)tgv_persist, grid, block, args, 0, stream);
}

// Round 7
// 275.894 us; speedup vs baseline: 3.9844x; 3.9844x over previous
//
#include <hip/hip_runtime.h>
#include <math.h>

// TGV-2 PDHG, B=2, H=W=256, T=128.
// R7: back to the proven 16-launch trapezoid structure (R3, 396us), with:
//  - rectangular region 32 rows x 48 cols, TILE 16x32, halo 8:
//    256 blocks (all 256 CUs busy; R3 wasted work at 4.0x redundancy,
//    this is 3.0x), 384 threads (6 waves), each thread owns a 1x4 strip.
//  - packed f32 math: element loop on float2 ext-vectors -> v_pk_fma_f32 /
//    v_pk_mul_f32; boundary masks as 0/1 multiplicative mask vectors
//    (precomputed, thread-constant); projection via rsq+min.
//  - scalar ds_read_b32 for single-float edge neighbors (was b128).
// Persistent-kernel attempts (R4-R6) all hit an unexplained VGPR=56 +
// 160MB/dispatch fetch pathology regardless of barrier liveness; abandoned.

namespace {

typedef float v2f __attribute__((ext_vector_type(2)));

constexpr int kN = 2 * 256 * 256;
constexpr float kTau = 0.28867513459481287f;  // 1/sqrt(12) (f32)
constexpr float kSigma = kTau;
constexpr float kInv1pTau = 1.0f / (1.0f + kTau);

constexpr int RR = 32;          // region rows (H)
constexpr int RC = 48;          // region cols (W)
constexpr int A = RR * RC;      // 1536 floats per LDS array
constexpr int PAD = 64;         // rim-overread safety pads (front/back)
constexpr int TILE_R = 16;
constexpr int TILE_C = 32;
constexpr int HALO = 8;         // = iterations per launch
constexpr int NTHREADS = RR * (RC / 4);  // 384 = 6 waves

__device__ __forceinline__ float4 ld4(const float* p) {
  return *reinterpret_cast<const float4*>(p);
}
__device__ __forceinline__ void st4p(float* p, v2f a, v2f b) {
  float4 v;
  v.x = a.x; v.y = a.y; v.z = b.x; v.w = b.y;
  *reinterpret_cast<float4*>(p) = v;
}

// ws layout: 10 arrays of kN floats: ub, v1, v2, vb1, vb2, p1, p2, q11, q22, q12
__global__ __launch_bounds__(256) void init_kernel(const float* __restrict__ f,
                                                   float* __restrict__ u,
                                                   float* __restrict__ ws) {
  int n = blockIdx.x * 256 + threadIdx.x;
  float fv = f[n];
  u[n] = fv;
  ws[n] = fv;  // ub = u0
#pragma unroll
  for (int i = 1; i < 10; ++i) ws[i * kN + n] = 0.f;
}

__global__ __launch_bounds__(NTHREADS, 1) void tgv8_kernel(
    const float* __restrict__ f, const float* __restrict__ rp,
    float* __restrict__ ug, float* __restrict__ ws) {
  float* ubg = ws + 0 * kN;
  float* v1g = ws + 1 * kN;
  float* v2g = ws + 2 * kN;
  float* vb1g = ws + 3 * kN;
  float* vb2g = ws + 4 * kN;
  float* p1g = ws + 5 * kN;
  float* p2g = ws + 6 * kN;
  float* q11g = ws + 7 * kN;
  float* q22g = ws + 8 * kN;
  float* q12g = ws + 9 * kN;

  __shared__ __align__(16) float smem[PAD + 8 * A + PAD];
  float* ubS = smem + PAD;
  float* vb1S = ubS + A;
  float* vb2S = vb1S + A;
  float* p1S = vb2S + A;
  float* p2S = p1S + A;
  float* q11S = p2S + A;
  float* q22S = q11S + A;
  float* q12S = q22S + A;

  const int tid = threadIdx.x;
  const int r = tid / 12;       // region row 0..31
  const int c = (tid % 12) * 4; // region col (float4-aligned)
  const int rc = r * RC + c;

  const int gi = blockIdx.y * TILE_R + r - HALO;  // global row (may be OOB)
  const int gj = blockIdx.x * TILE_C + c - HALO;  // global col
  const bool inImg = ((unsigned)gi < 256u) && ((unsigned)gj < 256u);
  const int base = blockIdx.z * 65536 + gi * 256 + gj;

  const float alpha0 = rp[0];
  const float alpha1 = rp[1];

  // ---- boundary masks as 0/1 multipliers (thread-constant) ----
  const float mD = (gi != 255) ? 1.f : 0.f;  // has down neighbor (H fwd)
  const float mU = (gi != 0) ? 1.f : 0.f;    // has up neighbor (H bwd)
  v2f mR0, mR1, mL0, mL1;                    // right/left masks per element
  mR0.x = (gj + 0 != 255) ? 1.f : 0.f;
  mR0.y = (gj + 1 != 255) ? 1.f : 0.f;
  mR1.x = (gj + 2 != 255) ? 1.f : 0.f;
  mR1.y = (gj + 3 != 255) ? 1.f : 0.f;
  mL0.x = (gj != 0) ? 1.f : 0.f;
  mL0.y = 1.f;
  mL1.x = 1.f;
  mL1.y = 1.f;

  // state: pairs of packed f32 (elements 01 / 23)
  v2f u_[2], ub_[2], v1_[2], v2_[2], vb1_[2], vb2_[2];
  v2f p1_[2], p2_[2], q11_[2], q22_[2], q12_[2], f_[2];

#define LOADV(dst, src)                              \
  {                                                  \
    float4 t_ = ld4((src) + base);                   \
    dst[0].x = t_.x; dst[0].y = t_.y;                \
    dst[1].x = t_.z; dst[1].y = t_.w;                \
  }
  if (inImg) {
    LOADV(f_, f)
    LOADV(u_, ug)
    LOADV(ub_, ubg)
    LOADV(v1_, v1g)
    LOADV(v2_, v2g)
    LOADV(vb1_, vb1g)
    LOADV(vb2_, vb2g)
    LOADV(p1_, p1g)
    LOADV(p2_, p2g)
    LOADV(q11_, q11g)
    LOADV(q22_, q22g)
    LOADV(q12_, q12g)
  } else {
#pragma unroll
    for (int h = 0; h < 2; ++h) {
      f_[h] = 0.f; u_[h] = 0.f; ub_[h] = 0.f;
      v1_[h] = 0.f; v2_[h] = 0.f; vb1_[h] = 0.f; vb2_[h] = 0.f;
      p1_[h] = 0.f; p2_[h] = 0.f; q11_[h] = 0.f; q22_[h] = 0.f; q12_[h] = 0.f;
    }
  }
#undef LOADV

  for (int t = 0; t < HALO; ++t) {
    // ---- publish dual halos (ub, vb) ----
    st4p(ubS + rc, ub_[0], ub_[1]);
    st4p(vb1S + rc, vb1_[0], vb1_[1]);
    st4p(vb2S + rc, vb2_[0], vb2_[1]);
    __syncthreads();

    // ---- dual ascent + projections ----
    const float ubX = ubS[rc + 4];    // right-edge scalar neighbors
    const float vb1X = vb1S[rc + 4];
    const float vb2X = vb2S[rc + 4];
    float4 td;
    td = ld4(ubS + rc + RC);
    v2f ubD[2];  ubD[0].x = td.x; ubD[0].y = td.y; ubD[1].x = td.z; ubD[1].y = td.w;
    td = ld4(vb1S + rc + RC);
    v2f vb1D[2]; vb1D[0].x = td.x; vb1D[0].y = td.y; vb1D[1].x = td.z; vb1D[1].y = td.w;
    td = ld4(vb2S + rc + RC);
    v2f vb2D[2]; vb2D[0].x = td.x; vb2D[0].y = td.y; vb2D[1].x = td.z; vb2D[1].y = td.w;

    // right-shifted values (element e+1)
    v2f ubr[2], vb1r[2], vb2r[2];
    ubr[0].x = ub_[0].y;  ubr[0].y = ub_[1].x;  ubr[1].x = ub_[1].y;  ubr[1].y = ubX;
    vb1r[0].x = vb1_[0].y; vb1r[0].y = vb1_[1].x; vb1r[1].x = vb1_[1].y; vb1r[1].y = vb1X;
    vb2r[0].x = vb2_[0].y; vb2r[0].y = vb2_[1].x; vb2r[1].x = vb2_[1].y; vb2r[1].y = vb2X;

#pragma unroll
    for (int h = 0; h < 2; ++h) {
      const v2f mR = h ? mR1 : mR0;
      // p update
      const v2f du1 = mD * (ubD[h] - ub_[h]);
      const v2f du2 = mR * (ubr[h] - ub_[h]);
      const v2f pn1 = p1_[h] + kSigma * (du1 - vb1_[h]);
      const v2f pn2 = p2_[h] + kSigma * (du2 - vb2_[h]);
      const v2f n2p = pn1 * pn1 + pn2 * pn2;
      v2f sp;
      sp.x = fminf(1.f, alpha1 * __builtin_amdgcn_rsqf(n2p.x));
      sp.y = fminf(1.f, alpha1 * __builtin_amdgcn_rsqf(n2p.y));
      p1_[h] = pn1 * sp;
      p2_[h] = pn2 * sp;

      // q update (e11, e22, e12)
      const v2f e11 = mD * (vb1D[h] - vb1_[h]);
      const v2f e22 = mR * (vb2r[h] - vb2_[h]);
      const v2f e12 =
          0.5f * (mR * (vb1r[h] - vb1_[h]) + mD * (vb2D[h] - vb2_[h]));
      const v2f qn1 = q11_[h] + kSigma * e11;
      const v2f qn2 = q22_[h] + kSigma * e22;
      const v2f qn3 = q12_[h] + kSigma * e12;
      const v2f n2q = qn1 * qn1 + qn2 * qn2 + 2.f * (qn3 * qn3);
      v2f sq;
      sq.x = fminf(1.f, alpha0 * __builtin_amdgcn_rsqf(n2q.x));
      sq.y = fminf(1.f, alpha0 * __builtin_amdgcn_rsqf(n2q.y));
      q11_[h] = qn1 * sq;
      q22_[h] = qn2 * sq;
      q12_[h] = qn3 * sq;
    }

    // ---- publish primal halos (new p, q) ----
    st4p(p1S + rc, p1_[0], p1_[1]);
    st4p(p2S + rc, p2_[0], p2_[1]);
    st4p(q11S + rc, q11_[0], q11_[1]);
    st4p(q22S + rc, q22_[0], q22_[1]);
    st4p(q12S + rc, q12_[0], q12_[1]);
    __syncthreads();

    // ---- primal descent + over-relaxation ----
    float4 tu;
    tu = ld4(p1S + rc - RC);
    v2f p1U[2];  p1U[0].x = tu.x; p1U[0].y = tu.y; p1U[1].x = tu.z; p1U[1].y = tu.w;
    tu = ld4(q11S + rc - RC);
    v2f q11U[2]; q11U[0].x = tu.x; q11U[0].y = tu.y; q11U[1].x = tu.z; q11U[1].y = tu.w;
    tu = ld4(q12S + rc - RC);
    v2f q12U[2]; q12U[0].x = tu.x; q12U[0].y = tu.y; q12U[1].x = tu.z; q12U[1].y = tu.w;
    const float p2Ls = p2S[rc - 1];   // left-edge scalar neighbors
    const float q22Ls = q22S[rc - 1];
    const float q12Ls = q12S[rc - 1];

    // left-shifted values (element e-1)
    v2f p2l[2], q22l[2], q12l[2];
    p2l[0].x = p2Ls;       p2l[0].y = p2_[0].x;
    p2l[1].x = p2_[0].y;   p2l[1].y = p2_[1].x;
    q22l[0].x = q22Ls;     q22l[0].y = q22_[0].x;
    q22l[1].x = q22_[0].y; q22l[1].y = q22_[1].x;
    q12l[0].x = q12Ls;     q12l[0].y = q12_[0].x;
    q12l[1].x = q12_[0].y; q12l[1].y = q12_[1].x;

#pragma unroll
    for (int h = 0; h < 2; ++h) {
      const v2f mR = h ? mR1 : mR0;
      const v2f mL = h ? mL1 : mL0;

      const v2f divp =
          mD * p1_[h] + mR * p2_[h] - (mU * p1U[h] + mL * p2l[h]);
      const v2f un = (u_[h] + kTau * divp + kTau * f_[h]) * kInv1pTau;
      ub_[h] = 2.f * un - u_[h];
      u_[h] = un;

      const v2f c1 =
          mD * q11_[h] + mR * q12_[h] - (mU * q11U[h] + mL * q12l[h]);
      const v2f c2 =
          mD * q12_[h] + mR * q22_[h] - (mU * q12U[h] + mL * q22l[h]);
      const v2f v1n = v1_[h] + kTau * (p1_[h] + c1);
      const v2f v2n = v2_[h] + kTau * (p2_[h] + c2);
      vb1_[h] = 2.f * v1n - v1_[h];
      v1_[h] = v1n;
      vb2_[h] = 2.f * v2n - v2_[h];
      v2_[h] = v2n;
    }
  }

  // ---- store interior 16x32 (exact after 8 iters) ----
  if (r >= HALO && r < HALO + TILE_R && c >= HALO && c < HALO + TILE_C) {
    st4p(ug + base, u_[0], u_[1]);
    st4p(ubg + base, ub_[0], ub_[1]);
    st4p(v1g + base, v1_[0], v1_[1]);
    st4p(v2g + base, v2_[0], v2_[1]);
    st4p(vb1g + base, vb1_[0], vb1_[1]);
    st4p(vb2g + base, vb2_[0], vb2_[1]);
    st4p(p1g + base, p1_[0], p1_[1]);
    st4p(p2g + base, p2_[0], p2_[1]);
    st4p(q11g + base, q11_[0], q11_[1]);
    st4p(q22g + base, q22_[0], q22_[1]);
    st4p(q12g + base, q12_[0], q12_[1]);
  }
}

}  // namespace

extern "C" void kernel_launch(void* const* d_in, const int* in_sizes, int n_in,
                              void* d_out, int out_size, void* d_ws,
                              size_t ws_size, hipStream_t stream) {
  const float* f = (const float*)d_in[0];
  const float* rp = (const float*)d_in[1];  // [alpha0, alpha1]
  // d_in[2] is T = 128 (fixed; trip count must be static for graph capture).

  float* u = (float*)d_out;
  float* ws = (float*)d_ws;

  hipLaunchKernelGGL(init_kernel, dim3(kN / 256), dim3(256), 0, stream, f, u,
                     ws);
  dim3 grid(256 / TILE_C, 256 / TILE_R, 2);  // 8 x 16 x 2 = 256 blocks
  for (int t = 0; t < 128 / HALO; ++t) {     // 16 launches x 8 iterations
    hipLaunchKernelGGL(tgv8_kernel, grid, dim3(NTHREADS), 0, stream, f, rp, u,
                       ws);
  }
}

// Round 8
// 261.230 us; speedup vs baseline: 4.2081x; 1.0561x over previous
//
#include <hip/hip_runtime.h>
#include <math.h>

// TGV-2 PDHG, B=2, H=W=256, T=128.
// R8: R7's geometry (16-launch trapezoid, region 32 rows x 48 cols, tile
// 16x32, halo 8 = 8 iters/launch, 256 blocks = 1/CU, 3.0x redundancy) with
// thread granularity halved: 768 threads (12 waves/CU, 3/SIMD), each thread
// owns a 1x2 strip (one packed v2f per field). R7 ran 6 waves/CU (1.5/SIMD)
// and sat latency-bound: 16 barriers/launch each exposed the LDS
// publish->read chain (~17us/dispatch vs ~5us pipe-sum). Doubling resident
// waves hides that latency; total VALU/LDS work is unchanged.
// Packed f32 math (v_pk_*), 0/1 multiplicative boundary masks, rsq+min
// projection (absmax 1.1e-8 in R7).

namespace {

typedef float v2f __attribute__((ext_vector_type(2)));

constexpr int kN = 2 * 256 * 256;
constexpr float kTau = 0.28867513459481287f;  // 1/sqrt(12) (f32)
constexpr float kSigma = kTau;
constexpr float kInv1pTau = 1.0f / (1.0f + kTau);

constexpr int RR = 32;          // region rows (H)
constexpr int RC = 48;          // region cols (W)
constexpr int A = RR * RC;      // 1536 floats per LDS array
constexpr int PAD = 64;         // rim-overread safety pads (front/back)
constexpr int TILE_R = 16;
constexpr int TILE_C = 32;
constexpr int HALO = 8;         // = iterations per launch
constexpr int NTHREADS = RR * (RC / 2);  // 768 = 12 waves

__device__ __forceinline__ float msel(bool m, float x) { return m ? x : 0.f; }

// ws layout: 10 arrays of kN floats: ub, v1, v2, vb1, vb2, p1, p2, q11, q22, q12
__global__ __launch_bounds__(256) void init_kernel(const float* __restrict__ f,
                                                   float* __restrict__ u,
                                                   float* __restrict__ ws) {
  int n = blockIdx.x * 256 + threadIdx.x;
  float fv = f[n];
  u[n] = fv;
  ws[n] = fv;  // ub = u0
#pragma unroll
  for (int i = 1; i < 10; ++i) ws[i * kN + n] = 0.f;
}

__global__ __launch_bounds__(NTHREADS, 1) void tgv8_kernel(
    const float* __restrict__ f, const float* __restrict__ rp,
    float* __restrict__ ug, float* __restrict__ ws) {
  float* ubg = ws + 0 * kN;
  float* v1g = ws + 1 * kN;
  float* v2g = ws + 2 * kN;
  float* vb1g = ws + 3 * kN;
  float* vb2g = ws + 4 * kN;
  float* p1g = ws + 5 * kN;
  float* p2g = ws + 6 * kN;
  float* q11g = ws + 7 * kN;
  float* q22g = ws + 8 * kN;
  float* q12g = ws + 9 * kN;

  __shared__ __align__(16) float smem[PAD + 8 * A + PAD];
  float* ubS = smem + PAD;
  float* vb1S = ubS + A;
  float* vb2S = vb1S + A;
  float* p1S = vb2S + A;
  float* p2S = p1S + A;
  float* q11S = p2S + A;
  float* q22S = q11S + A;
  float* q12S = q22S + A;

  const int tid = threadIdx.x;
  const int r = tid / 24;        // region row 0..31
  const int c = (tid % 24) * 2;  // region col (float2-aligned)
  const int rc = r * RC + c;

  const int gi = blockIdx.y * TILE_R + r - HALO;  // global row (may be OOB)
  const int gj = blockIdx.x * TILE_C + c - HALO;  // global col (even)
  const bool inImg = ((unsigned)gi < 256u) && ((unsigned)gj < 256u);
  const int base = blockIdx.z * 65536 + gi * 256 + gj;

  const float alpha0 = rp[0];
  const float alpha1 = rp[1];

  // ---- boundary masks as 0/1 multipliers (thread-constant) ----
  const float mD = (gi != 255) ? 1.f : 0.f;  // has down neighbor (H fwd)
  const float mU = (gi != 0) ? 1.f : 0.f;    // has up neighbor (H bwd)
  v2f mR, mL;
  mR.x = (gj + 0 != 255) ? 1.f : 0.f;
  mR.y = (gj + 1 != 255) ? 1.f : 0.f;
  mL.x = (gj != 0) ? 1.f : 0.f;
  mL.y = 1.f;

  // state: one packed v2f per field
  v2f u_, ub_, v1_, v2_, vb1_, vb2_, p1_, p2_, q11_, q22_, q12_, f_;

#define LOADV(dst, src) dst = *reinterpret_cast<const v2f*>((src) + base);
  if (inImg) {
    LOADV(f_, f)
    LOADV(u_, ug)
    LOADV(ub_, ubg)
    LOADV(v1_, v1g)
    LOADV(v2_, v2g)
    LOADV(vb1_, vb1g)
    LOADV(vb2_, vb2g)
    LOADV(p1_, p1g)
    LOADV(p2_, p2g)
    LOADV(q11_, q11g)
    LOADV(q22_, q22g)
    LOADV(q12_, q12g)
  } else {
    f_ = 0.f; u_ = 0.f; ub_ = 0.f;
    v1_ = 0.f; v2_ = 0.f; vb1_ = 0.f; vb2_ = 0.f;
    p1_ = 0.f; p2_ = 0.f; q11_ = 0.f; q22_ = 0.f; q12_ = 0.f;
  }
#undef LOADV

  for (int t = 0; t < HALO; ++t) {
    // ---- publish dual halos (ub, vb) ----
    *reinterpret_cast<v2f*>(ubS + rc) = ub_;
    *reinterpret_cast<v2f*>(vb1S + rc) = vb1_;
    *reinterpret_cast<v2f*>(vb2S + rc) = vb2_;
    __syncthreads();

    // ---- dual ascent + projections ----
    const float ubX = ubS[rc + 2];    // right-edge scalar neighbors
    const float vb1X = vb1S[rc + 2];
    const float vb2X = vb2S[rc + 2];
    const v2f ubD = *reinterpret_cast<const v2f*>(ubS + rc + RC);
    const v2f vb1D = *reinterpret_cast<const v2f*>(vb1S + rc + RC);
    const v2f vb2D = *reinterpret_cast<const v2f*>(vb2S + rc + RC);

    v2f ubr, vb1r, vb2r;  // right-shifted (element e+1)
    ubr.x = ub_.y;   ubr.y = ubX;
    vb1r.x = vb1_.y; vb1r.y = vb1X;
    vb2r.x = vb2_.y; vb2r.y = vb2X;

    // p update
    const v2f du1 = mD * (ubD - ub_);
    const v2f du2 = mR * (ubr - ub_);
    const v2f pn1 = p1_ + kSigma * (du1 - vb1_);
    const v2f pn2 = p2_ + kSigma * (du2 - vb2_);
    const v2f n2p = pn1 * pn1 + pn2 * pn2;
    v2f sp;
    sp.x = fminf(1.f, alpha1 * __builtin_amdgcn_rsqf(n2p.x));
    sp.y = fminf(1.f, alpha1 * __builtin_amdgcn_rsqf(n2p.y));
    p1_ = pn1 * sp;
    p2_ = pn2 * sp;

    // q update (e11, e22, e12)
    const v2f e11 = mD * (vb1D - vb1_);
    const v2f e22 = mR * (vb2r - vb2_);
    const v2f e12 = 0.5f * (mR * (vb1r - vb1_) + mD * (vb2D - vb2_));
    const v2f qn1 = q11_ + kSigma * e11;
    const v2f qn2 = q22_ + kSigma * e22;
    const v2f qn3 = q12_ + kSigma * e12;
    const v2f n2q = qn1 * qn1 + qn2 * qn2 + 2.f * (qn3 * qn3);
    v2f sq;
    sq.x = fminf(1.f, alpha0 * __builtin_amdgcn_rsqf(n2q.x));
    sq.y = fminf(1.f, alpha0 * __builtin_amdgcn_rsqf(n2q.y));
    q11_ = qn1 * sq;
    q22_ = qn2 * sq;
    q12_ = qn3 * sq;

    // ---- publish primal halos (new p, q) ----
    *reinterpret_cast<v2f*>(p1S + rc) = p1_;
    *reinterpret_cast<v2f*>(p2S + rc) = p2_;
    *reinterpret_cast<v2f*>(q11S + rc) = q11_;
    *reinterpret_cast<v2f*>(q22S + rc) = q22_;
    *reinterpret_cast<v2f*>(q12S + rc) = q12_;
    __syncthreads();

    // ---- primal descent + over-relaxation ----
    const v2f p1U = *reinterpret_cast<const v2f*>(p1S + rc - RC);
    const v2f q11U = *reinterpret_cast<const v2f*>(q11S + rc - RC);
    const v2f q12U = *reinterpret_cast<const v2f*>(q12S + rc - RC);
    const float p2Ls = p2S[rc - 1];   // left-edge scalar neighbors
    const float q22Ls = q22S[rc - 1];
    const float q12Ls = q12S[rc - 1];

    v2f p2l, q22l, q12l;  // left-shifted (element e-1)
    p2l.x = p2Ls;   p2l.y = p2_.x;
    q22l.x = q22Ls; q22l.y = q22_.x;
    q12l.x = q12Ls; q12l.y = q12_.x;

    const v2f divp = mD * p1_ + mR * p2_ - (mU * p1U + mL * p2l);
    const v2f un = (u_ + kTau * divp + kTau * f_) * kInv1pTau;
    ub_ = 2.f * un - u_;
    u_ = un;

    const v2f c1 = mD * q11_ + mR * q12_ - (mU * q11U + mL * q12l);
    const v2f c2 = mD * q12_ + mR * q22_ - (mU * q12U + mL * q22l);
    const v2f v1n = v1_ + kTau * (p1_ + c1);
    const v2f v2n = v2_ + kTau * (p2_ + c2);
    vb1_ = 2.f * v1n - v1_;
    v1_ = v1n;
    vb2_ = 2.f * v2n - v2_;
    v2_ = v2n;
  }

  // ---- store interior 16x32 (exact after 8 iters) ----
  if (r >= HALO && r < HALO + TILE_R && c >= HALO && c < HALO + TILE_C) {
#define STOREV(src, dst) *reinterpret_cast<v2f*>((dst) + base) = src;
    STOREV(u_, ug)
    STOREV(ub_, ubg)
    STOREV(v1_, v1g)
    STOREV(v2_, v2g)
    STOREV(vb1_, vb1g)
    STOREV(vb2_, vb2g)
    STOREV(p1_, p1g)
    STOREV(p2_, p2g)
    STOREV(q11_, q11g)
    STOREV(q22_, q22g)
    STOREV(q12_, q12g)
#undef STOREV
  }
}

}  // namespace

extern "C" void kernel_launch(void* const* d_in, const int* in_sizes, int n_in,
                              void* d_out, int out_size, void* d_ws,
                              size_t ws_size, hipStream_t stream) {
  const float* f = (const float*)d_in[0];
  const float* rp = (const float*)d_in[1];  // [alpha0, alpha1]
  // d_in[2] is T = 128 (fixed; trip count must be static for graph capture).

  float* u = (float*)d_out;
  float* ws = (float*)d_ws;

  hipLaunchKernelGGL(init_kernel, dim3(kN / 256), dim3(256), 0, stream, f, u,
                     ws);
  dim3 grid(256 / TILE_C, 256 / TILE_R, 2);  // 8 x 16 x 2 = 256 blocks
  for (int t = 0; t < 128 / HALO; ++t) {     // 16 launches x 8 iterations
    hipLaunchKernelGGL(tgv8_kernel, grid, dim3(NTHREADS), 0, stream, f, rp, u,
                       ws);
  }
}

// Round 9
// 255.802 us; speedup vs baseline: 4.2973x; 1.0212x over previous
//
#include <hip/hip_runtime.h>
#include <math.h>

// TGV-2 PDHG, B=2, H=W=256, T=128.
// R9 = R8 (16-launch trapezoid, region 32x48, tile 16x32, halo 8, 256 blocks
// = 1/CU, 768 threads = 12 waves, 1x2 strips, packed v_pk_f32 math, 0/1
// mask multipliers, rsq+min projection) plus:
//  - init folded into launch 0 (t0 arg; round 0 derives u=ub=f, rest 0);
//  - final launch stores only u (ws is dead after);
//  - vb1/vb2 interleaved pair array in LDS: publish b128 (was 2xb64),
//    down-read b128 (was 2xb64), right-read b64 (was 2xb32).
// Persistent-kernel path abandoned for good: device-scope fences invalidate
// per-XCD L2 for coherence -> 160MB HBM refetch/dispatch (R4-R6). Inter-launch
// data handoff rides Infinity Cache for free.

namespace {

typedef float v2f __attribute__((ext_vector_type(2)));

constexpr int kN = 2 * 256 * 256;
constexpr float kTau = 0.28867513459481287f;  // 1/sqrt(12) (f32)
constexpr float kSigma = kTau;
constexpr float kInv1pTau = 1.0f / (1.0f + kTau);

constexpr int RR = 32;          // region rows (H)
constexpr int RC = 48;          // region cols (W)
constexpr int A = RR * RC;      // 1536 floats per LDS array
constexpr int PAD = 64;         // rim-overread safety pads (front/back)
constexpr int TILE_R = 16;
constexpr int TILE_C = 32;
constexpr int HALO = 8;         // = iterations per launch
constexpr int NLAUNCH = 128 / HALO;      // 16
constexpr int NTHREADS = RR * (RC / 2);  // 768 = 12 waves

__device__ __forceinline__ float4 ld4(const float* p) {
  return *reinterpret_cast<const float4*>(p);
}

// ws layout: 10 arrays of kN floats: ub, v1, v2, vb1, vb2, p1, p2, q11, q22, q12
__global__ __launch_bounds__(NTHREADS, 3) void tgv8_kernel(
    const float* __restrict__ f, const float* __restrict__ rp,
    float* __restrict__ ug, float* __restrict__ ws, int t0) {
  float* ubg = ws + 0 * kN;
  float* v1g = ws + 1 * kN;
  float* v2g = ws + 2 * kN;
  float* vb1g = ws + 3 * kN;
  float* vb2g = ws + 4 * kN;
  float* p1g = ws + 5 * kN;
  float* p2g = ws + 6 * kN;
  float* q11g = ws + 7 * kN;
  float* q22g = ws + 8 * kN;
  float* q12g = ws + 9 * kN;

  // LDS: ub (A) + vb-pair (2A) + p1,p2,q11,q22,q12 (5A) = 8A floats
  __shared__ __align__(16) float smem[PAD + 8 * A + PAD];
  float* ubS = smem + PAD;
  float* vbS = ubS + A;       // interleaved [vb1, vb2] per pixel, 2A floats
  float* p1S = vbS + 2 * A;
  float* p2S = p1S + A;
  float* q11S = p2S + A;
  float* q22S = q11S + A;
  float* q12S = q22S + A;

  const int tid = threadIdx.x;
  const int r = tid / 24;        // region row 0..31
  const int c = (tid % 24) * 2;  // region col (float2-aligned)
  const int rc = r * RC + c;

  const int gi = blockIdx.y * TILE_R + r - HALO;  // global row (may be OOB)
  const int gj = blockIdx.x * TILE_C + c - HALO;  // global col (even)
  const bool inImg = ((unsigned)gi < 256u) && ((unsigned)gj < 256u);
  const int base = blockIdx.z * 65536 + gi * 256 + gj;

  const float alpha0 = rp[0];
  const float alpha1 = rp[1];

  // ---- boundary masks as 0/1 multipliers (thread-constant) ----
  const float mD = (gi != 255) ? 1.f : 0.f;  // has down neighbor (H fwd)
  const float mU = (gi != 0) ? 1.f : 0.f;    // has up neighbor (H bwd)
  v2f mR, mL;
  mR.x = (gj + 0 != 255) ? 1.f : 0.f;
  mR.y = (gj + 1 != 255) ? 1.f : 0.f;
  mL.x = (gj != 0) ? 1.f : 0.f;
  mL.y = 1.f;

  // state: one packed v2f per field
  v2f u_, ub_, v1_, v2_, vb1_, vb2_, p1_, p2_, q11_, q22_, q12_, f_;

#define LOADV(dst, src) dst = *reinterpret_cast<const v2f*>((src) + base);
  if (inImg) {
    LOADV(f_, f)
    if (t0 == 0) {
      // PDHG initial state: u = ub = f, everything else zero.
      u_ = f_; ub_ = f_;
      v1_ = 0.f; v2_ = 0.f; vb1_ = 0.f; vb2_ = 0.f;
      p1_ = 0.f; p2_ = 0.f; q11_ = 0.f; q22_ = 0.f; q12_ = 0.f;
    } else {
      LOADV(u_, ug)
      LOADV(ub_, ubg)
      LOADV(v1_, v1g)
      LOADV(v2_, v2g)
      LOADV(vb1_, vb1g)
      LOADV(vb2_, vb2g)
      LOADV(p1_, p1g)
      LOADV(p2_, p2g)
      LOADV(q11_, q11g)
      LOADV(q22_, q22g)
      LOADV(q12_, q12g)
    }
  } else {
    f_ = 0.f; u_ = 0.f; ub_ = 0.f;
    v1_ = 0.f; v2_ = 0.f; vb1_ = 0.f; vb2_ = 0.f;
    p1_ = 0.f; p2_ = 0.f; q11_ = 0.f; q22_ = 0.f; q12_ = 0.f;
  }
#undef LOADV

  for (int t = 0; t < HALO; ++t) {
    // ---- publish dual halos: ub (b64), vb pair (b128) ----
    *reinterpret_cast<v2f*>(ubS + rc) = ub_;
    {
      float4 vp;
      vp.x = vb1_.x; vp.y = vb2_.x; vp.z = vb1_.y; vp.w = vb2_.y;
      *reinterpret_cast<float4*>(vbS + 2 * rc) = vp;
    }
    __syncthreads();

    // ---- dual ascent + projections ----
    const float ubX = ubS[rc + 2];  // right-edge scalar neighbor
    const v2f vbX = *reinterpret_cast<const v2f*>(vbS + 2 * (rc + 2));
    const v2f ubD = *reinterpret_cast<const v2f*>(ubS + rc + RC);
    const float4 vd = ld4(vbS + 2 * (rc + RC));
    v2f vb1D, vb2D;
    vb1D.x = vd.x; vb1D.y = vd.z;
    vb2D.x = vd.y; vb2D.y = vd.w;

    v2f ubr, vb1r, vb2r;  // right-shifted (element e+1)
    ubr.x = ub_.y;   ubr.y = ubX;
    vb1r.x = vb1_.y; vb1r.y = vbX.x;
    vb2r.x = vb2_.y; vb2r.y = vbX.y;

    // p update
    const v2f du1 = mD * (ubD - ub_);
    const v2f du2 = mR * (ubr - ub_);
    const v2f pn1 = p1_ + kSigma * (du1 - vb1_);
    const v2f pn2 = p2_ + kSigma * (du2 - vb2_);
    const v2f n2p = pn1 * pn1 + pn2 * pn2;
    v2f sp;
    sp.x = fminf(1.f, alpha1 * __builtin_amdgcn_rsqf(n2p.x));
    sp.y = fminf(1.f, alpha1 * __builtin_amdgcn_rsqf(n2p.y));
    p1_ = pn1 * sp;
    p2_ = pn2 * sp;

    // q update (e11, e22, e12)
    const v2f e11 = mD * (vb1D - vb1_);
    const v2f e22 = mR * (vb2r - vb2_);
    const v2f e12 = 0.5f * (mR * (vb1r - vb1_) + mD * (vb2D - vb2_));
    const v2f qn1 = q11_ + kSigma * e11;
    const v2f qn2 = q22_ + kSigma * e22;
    const v2f qn3 = q12_ + kSigma * e12;
    const v2f n2q = qn1 * qn1 + qn2 * qn2 + 2.f * (qn3 * qn3);
    v2f sq;
    sq.x = fminf(1.f, alpha0 * __builtin_amdgcn_rsqf(n2q.x));
    sq.y = fminf(1.f, alpha0 * __builtin_amdgcn_rsqf(n2q.y));
    q11_ = qn1 * sq;
    q22_ = qn2 * sq;
    q12_ = qn3 * sq;

    // ---- publish primal halos (new p, q) ----
    *reinterpret_cast<v2f*>(p1S + rc) = p1_;
    *reinterpret_cast<v2f*>(p2S + rc) = p2_;
    *reinterpret_cast<v2f*>(q11S + rc) = q11_;
    *reinterpret_cast<v2f*>(q22S + rc) = q22_;
    *reinterpret_cast<v2f*>(q12S + rc) = q12_;
    __syncthreads();

    // ---- primal descent + over-relaxation ----
    const v2f p1U = *reinterpret_cast<const v2f*>(p1S + rc - RC);
    const v2f q11U = *reinterpret_cast<const v2f*>(q11S + rc - RC);
    const v2f q12U = *reinterpret_cast<const v2f*>(q12S + rc - RC);
    const float p2Ls = p2S[rc - 1];   // left-edge scalar neighbors
    const float q22Ls = q22S[rc - 1];
    const float q12Ls = q12S[rc - 1];

    v2f p2l, q22l, q12l;  // left-shifted (element e-1)
    p2l.x = p2Ls;   p2l.y = p2_.x;
    q22l.x = q22Ls; q22l.y = q22_.x;
    q12l.x = q12Ls; q12l.y = q12_.x;

    const v2f divp = mD * p1_ + mR * p2_ - (mU * p1U + mL * p2l);
    const v2f un = (u_ + kTau * divp + kTau * f_) * kInv1pTau;
    ub_ = 2.f * un - u_;
    u_ = un;

    const v2f c1 = mD * q11_ + mR * q12_ - (mU * q11U + mL * q12l);
    const v2f c2 = mD * q12_ + mR * q22_ - (mU * q12U + mL * q22l);
    const v2f v1n = v1_ + kTau * (p1_ + c1);
    const v2f v2n = v2_ + kTau * (p2_ + c2);
    vb1_ = 2.f * v1n - v1_;
    v1_ = v1n;
    vb2_ = 2.f * v2n - v2_;
    v2_ = v2n;
  }

  // ---- store interior 16x32 (exact after 8 iters) ----
  if (r >= HALO && r < HALO + TILE_R && c >= HALO && c < HALO + TILE_C) {
#define STOREV(src, dst) *reinterpret_cast<v2f*>((dst) + base) = src;
    STOREV(u_, ug)
    if (t0 != NLAUNCH - 1) {  // ws is dead after the final launch
      STOREV(ub_, ubg)
      STOREV(v1_, v1g)
      STOREV(v2_, v2g)
      STOREV(vb1_, vb1g)
      STOREV(vb2_, vb2g)
      STOREV(p1_, p1g)
      STOREV(p2_, p2g)
      STOREV(q11_, q11g)
      STOREV(q22_, q22g)
      STOREV(q12_, q12g)
    }
#undef STOREV
  }
}

}  // namespace

extern "C" void kernel_launch(void* const* d_in, const int* in_sizes, int n_in,
                              void* d_out, int out_size, void* d_ws,
                              size_t ws_size, hipStream_t stream) {
  const float* f = (const float*)d_in[0];
  const float* rp = (const float*)d_in[1];  // [alpha0, alpha1]
  // d_in[2] is T = 128 (fixed; trip count must be static for graph capture).

  float* u = (float*)d_out;
  float* ws = (float*)d_ws;

  dim3 grid(256 / TILE_C, 256 / TILE_R, 2);  // 8 x 16 x 2 = 256 blocks
  for (int t = 0; t < NLAUNCH; ++t) {        // 16 launches x 8 iterations
    hipLaunchKernelGGL(tgv8_kernel, grid, dim3(NTHREADS), 0, stream, f, rp, u,
                       ws, t);
  }
}